// Round 4
// baseline (151.450 us; speedup 1.0000x reference)
//
#include <hip/hip_runtime.h>

#define R 4096
#define NN 48
#define NP 49        // N+1
#define C 98         // 2N+2
#define NSEG 65536
#define MM (R * NN)  // 196608
#define GB_ROW (R / 2)              // 2048 blocks, 2 rows each (2 waves/row)
#define GB_HASH (MM / 256)          // 768 per level
#define GRID (GB_ROW + 2 * GB_HASH) // 3584

__device__ __forceinline__ float wscan_add(float v, int lane) {
#pragma unroll
    for (int d = 1; d < 64; d <<= 1) {
        float t = __shfl_up(v, d, 64);
        if (lane >= d) v += t;
    }
    return v;
}

__device__ __forceinline__ int wscan_max(int v, int lane) {
#pragma unroll
    for (int d = 1; d < 64; d <<= 1) {
        int t = __shfl_up(v, d, 64);
        if (lane >= d) v = max(v, t);
    }
    return v;
}

// Common tail: publish block partial with a release flag; the last block
// spin-waits on all flags and writes the final scalar. No same-address
// atomics anywhere (round-2 lesson: those serialize at ~15 ns each).
__device__ __forceinline__ void block_finish(float blocksum, float* partial,
                                             unsigned int* flags,
                                             float* __restrict__ out) {
    const int b = blockIdx.x;
    if (threadIdx.x == 0) {
        __hip_atomic_store(&partial[b], blocksum, __ATOMIC_RELAXED,
                           __HIP_MEMORY_SCOPE_AGENT);
        __hip_atomic_store(&flags[b], 1u, __ATOMIC_RELEASE,
                           __HIP_MEMORY_SCOPE_AGENT);
    }
    if (b == GRID - 1) {
        for (int t = threadIdx.x; t < GRID; t += 256) {
            while (__hip_atomic_load(&flags[t], __ATOMIC_ACQUIRE,
                                     __HIP_MEMORY_SCOPE_AGENT) != 1u)
                __builtin_amdgcn_s_sleep(1);
        }
        __syncthreads();
        float s = 0.f;
        for (int t = threadIdx.x; t < GRID; t += 256)
            s += __hip_atomic_load(&partial[t], __ATOMIC_RELAXED,
                                   __HIP_MEMORY_SCOPE_AGENT);
        const int lane = threadIdx.x & 63;
#pragma unroll
        for (int d = 32; d > 0; d >>= 1) s += __shfl_down(s, d, 64);
        __shared__ float sr[4];
        if (lane == 0) sr[threadIdx.x >> 6] = s;
        __syncthreads();
        if (threadIdx.x == 0) out[0] = sr[0] + sr[1] + sr[2] + sr[3];
    }
}

// ---------------------------------------------------------------------------
// Single fused kernel.
// Blocks [0, GB_ROW): 2 rows/block, 2 waves per row (interp + merge-rank +
//   distortion split across the row's wave pair; scans on the row's wave 0).
// Blocks [GB_ROW, GRID): hash-decay, ballot-based run lengths.
// ---------------------------------------------------------------------------
__global__ __launch_bounds__(256) void fused_kernel(
    const float* __restrict__ pd, const float* __restrict__ gt,
    const float* __restrict__ sdist_g, const float* __restrict__ w_g,
    const float* __restrict__ ps0, const float* __restrict__ pwt0,
    const float* __restrict__ ps1, const float* __restrict__ pwt1,
    const float* __restrict__ e0, const int* __restrict__ idx0,
    const float* __restrict__ e1, const int* __restrict__ idx1,
    float* __restrict__ partial, unsigned int* __restrict__ flags,
    float* __restrict__ out)
{
    __shared__ float s_sd[2][NP];
    __shared__ float s_wn[2][NN];
    __shared__ float s_w[2][NN];
    __shared__ float s_mid[2][NN];
    __shared__ float s_bounds[2][C];
    __shared__ float s_rs[2][C];
    __shared__ float s_wb[2][C];
    __shared__ float s_cdf[2][C];
    __shared__ int   s_fe[2][C];
    __shared__ float s_ci[2][257];
    __shared__ float s_red[4];
    __shared__ unsigned long long s_masks[6];

    const int tid = threadIdx.x;
    const int wid = tid >> 6;
    const int lane = tid & 63;

    if (blockIdx.x >= GB_ROW) {
        // ================= HASH part =================
        const int h = blockIdx.x - GB_ROW;
        const int lvlh = (h >= GB_HASH);
        const float* __restrict__ emb = lvlh ? e1 : e0;
        const int*   __restrict__ idx = lvlh ? idx1 : idx0;
        const int base = (lvlh ? h - GB_HASH : h) * 256;
        const int i = base + tid;

        const int seg = idx[i];
        const int head = (i == 0) || (idx[i - 1] != seg);
        unsigned long long m = __ballot(head);
        if (lane == 0) s_masks[wid + 1] = m;
        if (wid == 0) {
            const int j = base - 64 + lane;
            int hh = 0;
            if (j == 0) hh = 1;
            else if (j > 0) hh = (idx[j - 1] != idx[j]);
            unsigned long long mp = __ballot(hh);
            if (lane == 0) s_masks[0] = mp;
        }
        if (wid == 3) {
            const int j = base + 256 + lane;
            int hh = 1;                       // j >= MM: virtual terminator head
            if (j < MM) hh = (idx[j - 1] != idx[j]);
            unsigned long long mn = __ballot(hh);
            if (lane == 0) s_masks[5] = mn;
        }
        __syncthreads();

        const unsigned long long m_prev = s_masks[wid];
        const unsigned long long m_cur  = s_masks[wid + 1];
        const unsigned long long m_next = s_masks[wid + 2];
        const int wb0 = base + (wid << 6);

        const unsigned long long low = m_cur & (~0ULL >> (63 - lane));
        int s;
        if (low) s = wb0 + 63 - __builtin_clzll(low);
        else if (m_prev) s = wb0 - 64 + 63 - __builtin_clzll(m_prev);
        else { s = i; while (s > 0 && idx[s - 1] == seg) --s; }  // run>128: never

        const unsigned long long high =
            (lane < 63) ? (m_cur & (~0ULL << (lane + 1))) : 0ULL;
        int e;
        if (high) e = wb0 + __builtin_ctzll(high);
        else if (m_next) e = wb0 + 64 + __builtin_ctzll(m_next);
        else { e = i + 1; while (e < MM && idx[e] == seg) ++e; }  // never

        const float a = emb[2 * i], b = emb[2 * i + 1];
        float v = (a * a + b * b) / (float)(e - s);

#pragma unroll
        for (int d = 32; d > 0; d >>= 1) v += __shfl_down(v, d, 64);
        if (lane == 0) s_red[wid] = v;
        __syncthreads();
        const float blocksum =
            (s_red[0] + s_red[1] + s_red[2] + s_red[3]) *
            (0.1f / ((float)NSEG * 2.f));
        block_finish(blocksum, partial, flags, out);
        return;
    }

    // ================= ROW part: 2 rows, 2 waves per row =================
    const int rw = wid >> 1;      // row within block
    const int half = wid & 1;     // which wave of the row's pair
    const int r = blockIdx.x * 2 + rw;

    float* sd  = s_sd[rw];
    float* wn  = s_wn[rw];
    float* w   = s_w[rw];
    float* mid = s_mid[rw];
    float* bounds = s_bounds[rw];
    float* rs  = s_rs[rw];
    float* wb  = s_wb[rw];
    float* cdf = s_cdf[rw];
    int*   fe  = s_fe[rw];
    float* ci  = s_ci[rw];

    if (half == 0) {
        if (lane < NP) sd[lane] = sdist_g[r * NP + lane];
    } else {
        if (lane < NN) w[lane] = w_g[r * NN + lane];
    }
    __syncthreads();
    if (half == 0 && lane < NN) {
        wn[lane]  = w[lane] / (sd[lane + 1] - sd[lane] + 1e-8f);
        mid[lane] = 0.5f * (sd[lane + 1] + sd[lane]);
    }
    __syncthreads();

    float local = 0.f;

#pragma unroll
    for (int lvl = 0; lvl < 2; ++lvl) {
        const float pw = (lvl == 0) ? 0.01f : 0.005f;
        const int X = (lvl == 0) ? 257 : 97;
        const float* ps  = (lvl == 0) ? ps0 : ps1;
        const float* pwt = (lvl == 0) ? pwt0 : pwt1;

        // ---- stable merge-rank of cat = [sd-pw, sd+pw]; one search/wave ----
        if (lane < NP) {
            const int i = lane;
            const float dlo = (i > 0)  ? wn[i - 1] : 0.f;
            const float dhi = (i < NN) ? wn[i] : 0.f;
            const float rd = (dhi - dlo) / (2.f * pw);
            if (half == 0) {
                const float vlo = sd[i] - pw;
                int lo = 0, hi = NP;  // count second-half strictly < vlo
                while (lo < hi) { int m = (lo + hi) >> 1; if (sd[m] + pw < vlo) lo = m + 1; else hi = m; }
                bounds[i + lo] = vlo; rs[i + lo] = rd;
            } else {
                const float vhi = sd[i] + pw;
                int lo = 0, hi = NP;  // count first-half <= vhi (1st wins ties)
                while (lo < hi) { int m = (lo + hi) >> 1; if (sd[m] - pw <= vhi) lo = m + 1; else hi = m; }
                bounds[i + lo] = vhi; rs[i + lo] = -rd;
            }
        }
        __syncthreads();

        // ---- parallel scans (row's wave 0): elements k0=2*lane, k1=k0+1 ----
        if (half == 0) {
            const int k0 = 2 * lane, k1 = 2 * lane + 1;
            const bool v0 = (k0 <= C - 2), v1 = (k1 <= C - 2);
            float b0 = 0.f, b1 = 0.f, b2 = 0.f, r0 = 0.f, r1 = 0.f;
            if (v0) { b0 = bounds[k0]; b1 = bounds[k0 + 1]; r0 = rs[k0]; }
            if (v1) { b2 = bounds[k1 + 1]; r1 = rs[k1]; }
            const float ds0 = b1 - b0, ds1 = b2 - b1;

            // scan 1: cum1 = cumsum(radio_sorted)
            float pairv = r0 + r1;
            float incl = wscan_add(pairv, lane);
            float excl = __shfl_up(incl, 1, 64); if (lane == 0) excl = 0.f;
            const float cum0 = excl + r0, cum1 = excl + pairv;

            // scan 2: acc2 = cumsum(ds * cum1); rec = max(acc2, 0)
            float y0 = v0 ? ds0 * cum0 : 0.f;
            float y1 = v1 ? ds1 * cum1 : 0.f;
            pairv = y0 + y1;
            incl = wscan_add(pairv, lane);
            excl = __shfl_up(incl, 1, 64); if (lane == 0) excl = 0.f;
            const float rec0 = v0 ? fmaxf(excl + y0, 0.f) : 0.f;
            const float rec1 = v1 ? fmaxf(excl + pairv, 0.f) : 0.f;

            // scan 3: cdf = cumsum(0.5*(rec[k]+rec[k-1])*ds[k]), rec[-1]=0
            float rprev = __shfl_up(rec1, 1, 64); if (lane == 0) rprev = 0.f;
            float t0 = v0 ? 0.5f * (rec0 + rprev) * ds0 : 0.f;
            float t1 = v1 ? 0.5f * (rec1 + rec0) * ds1 : 0.f;
            pairv = t0 + t1;
            incl = wscan_add(pairv, lane);
            excl = __shfl_up(incl, 1, 64); if (lane == 0) excl = 0.f;
            const float c0 = excl + t0;     // cdf[j0], j0 = k0+1
            const float c1 = excl + pairv;  // cdf[j1], j1 = k1+1

            // first_eq (plateau start) = incl max-scan of (changed ? j : 0)
            float cprev = __shfl_up(c1, 1, 64); if (lane == 0) cprev = 0.f;
            const int j0 = k0 + 1, j1 = k1 + 1;
            const int m0 = (v0 && c0 != cprev) ? j0 : 0;
            const int m1 = (v1 && c1 != c0) ? j1 : 0;
            int pm = max(m0, m1);
            int inclm = wscan_max(pm, lane);
            int exclm = __shfl_up(inclm, 1, 64); if (lane == 0) exclm = 0;

            if (lane == 0) { wb[0] = 0.f; cdf[0] = 0.f; fe[0] = 0; }
            if (v0) { wb[j0] = rec0; cdf[j0] = c0; fe[j0] = max(exclm, m0); }
            if (v1) { wb[j1] = rec1; cdf[j1] = c1; fe[j1] = max(exclm, pm); }
        }
        __syncthreads();

        // ---- sorted_interp_quad across BOTH waves of the row ----
        for (int t = (half << 6) + lane; t < X; t += 128) {
            const float x = ps[r * X + t];
            int lo = 0, hi = C;
            while (lo < hi) { int m = (lo + hi) >> 1; if (bounds[m] <= x) lo = m + 1; else hi = m; }
            const int j = lo - 1;  // largest p with bounds[p] <= x, or -1
            float res = 0.f;
            if (j >= 0) {
                const float fcdf0 = cdf[j];
                const int   i0   = fe[j];          // argmax tie -> plateau start
                const float xp0  = bounds[j];
                float xp1; int i1;
                if (j == C - 1) { xp1 = bounds[C - 1]; i1 = 0; }
                else {
                    xp1 = bounds[j + 1];
                    i1 = (cdf[j + 1] == cdf[C - 1]) ? 0 : (j + 1);  // flat tail
                }
                const float fpdf0 = wb[i0], fpdf1 = wb[i1];
                const float dx = x - xp0, den = xp1 - xp0;
                float off;
                if (den != 0.f) off = dx / den;
                else off = (dx == 0.f) ? 0.f : ((dx > 0.f) ? 1.f : 0.f);
                off = fminf(fmaxf(off, 0.f), 1.f);
                res = fcdf0 + dx * (fpdf0 + fpdf1 * off + fpdf0 * (1.f - off)) * 0.5f;
            }
            ci[t] = res;
        }
        __syncthreads();

        float lsum = 0.f;
        for (int t = (half << 6) + lane; t < X - 1; t += 128) {
            const float ws = ci[t + 1] - ci[t];
            const float pv = pwt[r * (X - 1) + t];
            const float d = fmaxf(ws - pv, 0.f);
            lsum += d * d / (pv + 1e-5f);
        }
        local += lsum * (1.0f / ((float)R * (float)(X - 1)));  // W_INTER = 1
        __syncthreads();  // before LDS reuse by next level
    }

    // ---- distortion loss, split across the row's wave pair ----
    float p1 = 0.f;
    for (int t = (half << 6) + lane; t < NN * NN; t += 128) {
        const int n = t / NN, m2 = t - n * NN;
        p1 += w[n] * w[m2] * fabsf(mid[n] - mid[m2]);
    }
    local += p1 * (0.01f / (float)R);
    if (half == 0 && lane < NN) {
        const float dd = sd[lane + 1] - sd[lane];
        local += (w[lane] * w[lane] * dd) * (0.01f / (3.f * (float)R));
    }

    // ---- rgb loss ----
    if (half == 0 && lane < 3) {
        const float e = pd[r * 3 + lane] - gt[r * 3 + lane];
        local += e * e * (1.0f / ((float)R * 3.f));
    }

    // ---- wave reduce, publish block partial ----
#pragma unroll
    for (int d = 32; d > 0; d >>= 1) local += __shfl_down(local, d, 64);
    if (lane == 0) s_red[wid] = local;
    __syncthreads();
    const float blocksum = s_red[0] + s_red[1] + s_red[2] + s_red[3];
    block_finish(blocksum, partial, flags, out);
}

extern "C" void kernel_launch(void* const* d_in, const int* in_sizes, int n_in,
                              void* d_out, int out_size, void* d_ws, size_t ws_size,
                              hipStream_t stream)
{
    const float* pd  = (const float*)d_in[0];
    const float* gt  = (const float*)d_in[1];
    const float* sd  = (const float*)d_in[2];
    const float* w   = (const float*)d_in[3];
    const float* ps0 = (const float*)d_in[4];
    const float* pw0 = (const float*)d_in[5];
    const float* ps1 = (const float*)d_in[6];
    const float* pw1 = (const float*)d_in[7];
    const float* e0  = (const float*)d_in[8];
    const float* e1  = (const float*)d_in[9];
    const int* i0    = (const int*)d_in[10];
    const int* i1    = (const int*)d_in[11];

    float* partial      = (float*)d_ws;                       // GRID floats
    unsigned int* flags = (unsigned int*)((char*)d_ws + 16384); // GRID flags

    hipLaunchKernelGGL(fused_kernel, dim3(GRID), dim3(256), 0, stream,
                       pd, gt, sd, w, ps0, pw0, ps1, pw1,
                       e0, i0, e1, i1, partial, flags, (float*)d_out);
}

// Round 5
// 107.253 us; speedup vs baseline: 1.4121x; 1.4121x over previous
//
#include <hip/hip_runtime.h>

#define R 4096
#define NN 48
#define NP 49        // N+1
#define C 98         // 2N+2
#define NSEG 65536
#define MM (R * NN)  // 196608
#define RPB 4        // rows (waves) per row-block
#define GB_ROW (R / RPB)            // 1024
#define GB_HASH (MM / 256)          // 768 per level
#define GRID (GB_ROW + 2 * GB_HASH) // 2560

// Zero-cost compiler fence: row LDS is wave-private, and DS ops from one
// wave are processed in order, so no s_barrier is needed — only a guard
// against compiler reordering of ds_write/ds_read.
#define WAVE_FENCE() __builtin_amdgcn_wave_barrier()

__device__ __forceinline__ float wscan_add(float v, int lane) {
#pragma unroll
    for (int d = 1; d < 64; d <<= 1) {
        float t = __shfl_up(v, d, 64);
        if (lane >= d) v += t;
    }
    return v;
}

__device__ __forceinline__ int wscan_max(int v, int lane) {
#pragma unroll
    for (int d = 1; d < 64; d <<= 1) {
        int t = __shfl_up(v, d, 64);
        if (lane >= d) v = max(v, t);
    }
    return v;
}

// ---------------------------------------------------------------------------
// Fused kernel. Blocks [0, GB_ROW): per-row losses, ONE wave per row, 4 rows
// per block, wave-private LDS, NO inter-wave barriers until the final reduce.
// Blocks [GB_ROW, GRID): hash-decay, ballot-based run lengths.
// Every block writes partial[blockIdx.x] with a plain store (no atomics).
// ---------------------------------------------------------------------------
__global__ __launch_bounds__(256) void fused_kernel(
    const float* __restrict__ pd, const float* __restrict__ gt,
    const float* __restrict__ sdist_g, const float* __restrict__ w_g,
    const float* __restrict__ ps0, const float* __restrict__ pwt0,
    const float* __restrict__ ps1, const float* __restrict__ pwt1,
    const float* __restrict__ e0, const int* __restrict__ idx0,
    const float* __restrict__ e1, const int* __restrict__ idx1,
    float* __restrict__ partial)
{
    __shared__ float s_sd[RPB][NP];
    __shared__ float s_wn[RPB][NN];
    __shared__ float s_w[RPB][NN];
    __shared__ float s_mid[RPB][NN];
    __shared__ float s_bounds[RPB][C];
    __shared__ float s_rs[RPB][C];
    __shared__ float s_wb[RPB][C];
    __shared__ float s_cdf[RPB][C];
    __shared__ int   s_fe[RPB][C];
    __shared__ float s_ci[RPB][260];
    __shared__ float s_red[RPB];
    __shared__ unsigned long long s_masks[6];

    const int tid = threadIdx.x;
    const int wid = tid >> 6;
    const int lane = tid & 63;

    if (blockIdx.x >= GB_ROW) {
        // ================= HASH part =================
        const int h = blockIdx.x - GB_ROW;
        const int lvlh = (h >= GB_HASH);
        const float* __restrict__ emb = lvlh ? e1 : e0;
        const int*   __restrict__ idx = lvlh ? idx1 : idx0;
        const int base = (lvlh ? h - GB_HASH : h) * 256;
        const int i = base + tid;

        const int seg = idx[i];
        const int head = (i == 0) || (idx[i - 1] != seg);
        unsigned long long m = __ballot(head);
        if (lane == 0) s_masks[wid + 1] = m;
        if (wid == 0) {
            const int j = base - 64 + lane;
            int hh = 0;
            if (j == 0) hh = 1;
            else if (j > 0) hh = (idx[j - 1] != idx[j]);
            unsigned long long mp = __ballot(hh);
            if (lane == 0) s_masks[0] = mp;
        }
        if (wid == 3) {
            const int j = base + 256 + lane;
            int hh = 1;                       // j >= MM: virtual terminator head
            if (j < MM) hh = (idx[j - 1] != idx[j]);
            unsigned long long mn = __ballot(hh);
            if (lane == 0) s_masks[5] = mn;
        }
        __syncthreads();

        const unsigned long long m_prev = s_masks[wid];
        const unsigned long long m_cur  = s_masks[wid + 1];
        const unsigned long long m_next = s_masks[wid + 2];
        const int wb0 = base + (wid << 6);

        const unsigned long long low = m_cur & (~0ULL >> (63 - lane));
        int s;
        if (low) s = wb0 + 63 - __builtin_clzll(low);
        else if (m_prev) s = wb0 - 64 + 63 - __builtin_clzll(m_prev);
        else { s = i; while (s > 0 && idx[s - 1] == seg) --s; }  // run>128: never

        const unsigned long long high =
            (lane < 63) ? (m_cur & (~0ULL << (lane + 1))) : 0ULL;
        int e;
        if (high) e = wb0 + __builtin_ctzll(high);
        else if (m_next) e = wb0 + 64 + __builtin_ctzll(m_next);
        else { e = i + 1; while (e < MM && idx[e] == seg) ++e; }  // never

        const float a = emb[2 * i], b = emb[2 * i + 1];
        float v = (a * a + b * b) / (float)(e - s);

#pragma unroll
        for (int d = 32; d > 0; d >>= 1) v += __shfl_down(v, d, 64);
        if (lane == 0) s_red[wid] = v;
        __syncthreads();
        if (tid == 0)
            partial[blockIdx.x] =
                (s_red[0] + s_red[1] + s_red[2] + s_red[3]) *
                (0.1f / ((float)NSEG * 2.f));
        return;
    }

    // ================= ROW part: one wave per row, wave-private LDS =======
    const int r = blockIdx.x * RPB + wid;

    float* sd  = s_sd[wid];
    float* wn  = s_wn[wid];
    float* w   = s_w[wid];
    float* mid = s_mid[wid];
    float* bounds = s_bounds[wid];
    float* rs  = s_rs[wid];
    float* wb  = s_wb[wid];
    float* cdf = s_cdf[wid];
    int*   fe  = s_fe[wid];
    float* ci  = s_ci[wid];

    if (lane < NP) sd[lane] = sdist_g[r * NP + lane];
    if (lane < NN) w[lane] = w_g[r * NN + lane];
    WAVE_FENCE();
    if (lane < NN) {
        wn[lane]  = w[lane] / (sd[lane + 1] - sd[lane] + 1e-8f);
        mid[lane] = 0.5f * (sd[lane + 1] + sd[lane]);
    }
    WAVE_FENCE();

    float local = 0.f;

#pragma unroll
    for (int lvl = 0; lvl < 2; ++lvl) {
        const float pw = (lvl == 0) ? 0.01f : 0.005f;
        const int X = (lvl == 0) ? 257 : 97;
        const float* ps  = (lvl == 0) ? ps0 : ps1;
        const float* pwt = (lvl == 0) ? pwt0 : pwt1;

        // ---- stable merge-rank of cat = [sd-pw, sd+pw]; scatter ----
        if (lane < NP) {
            const int i = lane;
            const float dlo = (i > 0)  ? wn[i - 1] : 0.f;
            const float dhi = (i < NN) ? wn[i] : 0.f;
            const float rd = (dhi - dlo) / (2.f * pw);
            const float vlo = sd[i] - pw, vhi = sd[i] + pw;
            int lo = 0, hi = NP;  // count second-half strictly < vlo
            while (lo < hi) { int m = (lo + hi) >> 1; if (sd[m] + pw < vlo) lo = m + 1; else hi = m; }
            const int rlo = i + lo;
            lo = 0; hi = NP;      // count first-half <= vhi (first half wins ties)
            while (lo < hi) { int m = (lo + hi) >> 1; if (sd[m] - pw <= vhi) lo = m + 1; else hi = m; }
            const int rhi = i + lo;
            bounds[rlo] = vlo; rs[rlo] = rd;
            bounds[rhi] = vhi; rs[rhi] = -rd;
        }
        WAVE_FENCE();

        // ---- parallel scans: lane holds elements k0=2*lane, k1=k0+1 ----
        const int k0 = 2 * lane, k1 = 2 * lane + 1;
        const bool v0 = (k0 <= C - 2), v1 = (k1 <= C - 2);
        float b0 = 0.f, b1 = 0.f, b2 = 0.f, r0 = 0.f, r1 = 0.f;
        if (v0) { b0 = bounds[k0]; b1 = bounds[k0 + 1]; r0 = rs[k0]; }
        if (v1) { b2 = bounds[k1 + 1]; r1 = rs[k1]; }
        const float ds0 = b1 - b0, ds1 = b2 - b1;

        // scan 1: cum1 = cumsum(radio_sorted)
        float pairv = r0 + r1;
        float incl = wscan_add(pairv, lane);
        float excl = __shfl_up(incl, 1, 64); if (lane == 0) excl = 0.f;
        const float cum0 = excl + r0, cum1 = excl + pairv;

        // scan 2: acc2 = cumsum(ds * cum1); rec = max(acc2, 0)
        float y0 = v0 ? ds0 * cum0 : 0.f;
        float y1 = v1 ? ds1 * cum1 : 0.f;
        pairv = y0 + y1;
        incl = wscan_add(pairv, lane);
        excl = __shfl_up(incl, 1, 64); if (lane == 0) excl = 0.f;
        const float rec0 = v0 ? fmaxf(excl + y0, 0.f) : 0.f;
        const float rec1 = v1 ? fmaxf(excl + pairv, 0.f) : 0.f;

        // scan 3: cdf = cumsum(0.5*(rec[k]+rec[k-1])*ds[k]), rec[-1]=0
        float rprev = __shfl_up(rec1, 1, 64); if (lane == 0) rprev = 0.f;
        float t0 = v0 ? 0.5f * (rec0 + rprev) * ds0 : 0.f;
        float t1 = v1 ? 0.5f * (rec1 + rec0) * ds1 : 0.f;
        pairv = t0 + t1;
        incl = wscan_add(pairv, lane);
        excl = __shfl_up(incl, 1, 64); if (lane == 0) excl = 0.f;
        const float c0 = excl + t0;     // cdf[j0], j0 = k0+1
        const float c1 = excl + pairv;  // cdf[j1], j1 = k1+1

        // first_eq (plateau start) = inclusive max-scan of (changed ? j : 0)
        float cprev = __shfl_up(c1, 1, 64); if (lane == 0) cprev = 0.f;
        const int j0 = k0 + 1, j1 = k1 + 1;
        const int m0 = (v0 && c0 != cprev) ? j0 : 0;
        const int m1 = (v1 && c1 != c0) ? j1 : 0;
        int pm = max(m0, m1);
        int inclm = wscan_max(pm, lane);
        int exclm = __shfl_up(inclm, 1, 64); if (lane == 0) exclm = 0;

        if (lane == 0) { wb[0] = 0.f; cdf[0] = 0.f; fe[0] = 0; }
        if (v0) { wb[j0] = rec0; cdf[j0] = c0; fe[j0] = max(exclm, m0); }
        if (v1) { wb[j1] = rec1; cdf[j1] = c1; fe[j1] = max(exclm, pm); }
        // cdf_last for the whole wave (broadcast from the lane holding c at C-1)
        const float cdf_last = __shfl(c1, (C - 2) >> 1, 64);  // j1 == C-1
        WAVE_FENCE();

        // ---- sorted_interp_quad, exact argmax/argmin tie semantics ----
        for (int t = lane; t < X; t += 64) {
            const float x = ps[r * X + t];
            int lo = 0, hi = C;
            while (lo < hi) { int m = (lo + hi) >> 1; if (bounds[m] <= x) lo = m + 1; else hi = m; }
            const int j = lo - 1;  // largest p with bounds[p] <= x, or -1
            float res = 0.f;
            if (j >= 0) {
                const float fcdf0 = cdf[j];
                const int   i0   = fe[j];          // argmax tie -> plateau start
                const float xp0  = bounds[j];
                float xp1; int i1;
                if (j == C - 1) { xp1 = bounds[C - 1]; i1 = 0; }
                else {
                    xp1 = bounds[j + 1];
                    i1 = (cdf[j + 1] == cdf_last) ? 0 : (j + 1);  // flat tail
                }
                const float fpdf0 = wb[i0], fpdf1 = wb[i1];
                const float dx = x - xp0, den = xp1 - xp0;
                float off;
                if (den != 0.f) off = dx / den;
                else off = (dx == 0.f) ? 0.f : ((dx > 0.f) ? 1.f : 0.f);
                off = fminf(fmaxf(off, 0.f), 1.f);
                res = fcdf0 + dx * (fpdf0 + fpdf1 * off + fpdf0 * (1.f - off)) * 0.5f;
            }
            ci[t] = res;
        }
        WAVE_FENCE();

        float lsum = 0.f;
        for (int t = lane; t < X - 1; t += 64) {
            const float ws = ci[t + 1] - ci[t];
            const float pv = pwt[r * (X - 1) + t];
            const float d = fmaxf(ws - pv, 0.f);
            lsum += d * d / (pv + 1e-5f);
        }
        local += lsum * (1.0f / ((float)R * (float)(X - 1)));  // W_INTER = 1
        WAVE_FENCE();  // before LDS reuse by next level
    }

    // ---- distortion loss (all terms non-negative -> abs is identity) ----
    float p1 = 0.f;
    for (int t = lane; t < NN * NN; t += 64) {
        const int n = t / NN, m2 = t - n * NN;
        p1 += w[n] * w[m2] * fabsf(mid[n] - mid[m2]);
    }
    local += p1 * (0.01f / (float)R);
    if (lane < NN) {
        const float dd = sd[lane + 1] - sd[lane];
        local += (w[lane] * w[lane] * dd) * (0.01f / (3.f * (float)R));
    }

    // ---- rgb loss ----
    if (lane < 3) {
        const float e = pd[r * 3 + lane] - gt[r * 3 + lane];
        local += e * e * (1.0f / ((float)R * 3.f));
    }

    // ---- wave reduce, one real barrier, plain partial store ----
#pragma unroll
    for (int d = 32; d > 0; d >>= 1) local += __shfl_down(local, d, 64);
    if (lane == 0) s_red[wid] = local;
    __syncthreads();
    if (tid == 0)
        partial[blockIdx.x] = s_red[0] + s_red[1] + s_red[2] + s_red[3];
}

// ---------------------------------------------------------------------------
// Final reduction of per-block partials (single block, no atomics).
// ---------------------------------------------------------------------------
__global__ __launch_bounds__(256) void reduce_kernel(
    const float* __restrict__ partial, float* __restrict__ out)
{
    float s = 0.f;
    for (int t = threadIdx.x; t < GRID; t += 256) s += partial[t];
    const int lane = threadIdx.x & 63;
#pragma unroll
    for (int d = 32; d > 0; d >>= 1) s += __shfl_down(s, d, 64);
    __shared__ float sred[4];
    if (lane == 0) sred[threadIdx.x >> 6] = s;
    __syncthreads();
    if (threadIdx.x == 0)
        out[0] = sred[0] + sred[1] + sred[2] + sred[3];
}

extern "C" void kernel_launch(void* const* d_in, const int* in_sizes, int n_in,
                              void* d_out, int out_size, void* d_ws, size_t ws_size,
                              hipStream_t stream)
{
    const float* pd  = (const float*)d_in[0];
    const float* gt  = (const float*)d_in[1];
    const float* sd  = (const float*)d_in[2];
    const float* w   = (const float*)d_in[3];
    const float* ps0 = (const float*)d_in[4];
    const float* pw0 = (const float*)d_in[5];
    const float* ps1 = (const float*)d_in[6];
    const float* pw1 = (const float*)d_in[7];
    const float* e0  = (const float*)d_in[8];
    const float* e1  = (const float*)d_in[9];
    const int* i0    = (const int*)d_in[10];
    const int* i1    = (const int*)d_in[11];

    float* partial = (float*)d_ws;  // GRID floats; every slot written each call

    hipLaunchKernelGGL(fused_kernel, dim3(GRID), dim3(256), 0, stream,
                       pd, gt, sd, w, ps0, pw0, ps1, pw1,
                       e0, i0, e1, i1, partial);
    hipLaunchKernelGGL(reduce_kernel, dim3(1), dim3(256), 0, stream,
                       partial, (float*)d_out);
}

// Round 6
// 103.069 us; speedup vs baseline: 1.4694x; 1.0406x over previous
//
#include <hip/hip_runtime.h>

#define R 4096
#define NN 48
#define NP 49        // N+1
#define C 98         // 2N+2
#define NSEG 65536
#define MM (R * NN)  // 196608
#define RPB 4        // rows (waves) per row-block
#define GB_ROW (R / RPB)            // 1024
#define GB_HASH (MM / 256)          // 768 per level
#define GRID (GB_ROW + 2 * GB_HASH) // 2560

// Zero-cost compiler fence: row LDS is wave-private; DS ops from one wave are
// processed in order, so no s_barrier needed — just block compiler reordering.
#define WAVE_FENCE() __builtin_amdgcn_wave_barrier()

__device__ __forceinline__ float wscan_add(float v, int lane) {
#pragma unroll
    for (int d = 1; d < 64; d <<= 1) {
        float t = __shfl_up(v, d, 64);
        if (lane >= d) v += t;
    }
    return v;
}

__device__ __forceinline__ int wscan_max(int v, int lane) {
#pragma unroll
    for (int d = 1; d < 64; d <<= 1) {
        int t = __shfl_up(v, d, 64);
        if (lane >= d) v = max(v, t);
    }
    return v;
}

// ---------------------------------------------------------------------------
// Fused kernel. Blocks [0, GB_ROW): per-row losses, ONE wave per row, 4 rows
// per block, wave-private LDS, wave fences only (one s_barrier at the end).
// Blocks [GB_ROW, GRID): hash-decay, ballot-based run lengths.
// Every block writes partial[blockIdx.x] with a plain store (no atomics).
// ---------------------------------------------------------------------------
__global__ __launch_bounds__(256) void fused_kernel(
    const float* __restrict__ pd, const float* __restrict__ gt,
    const float* __restrict__ sdist_g, const float* __restrict__ w_g,
    const float* __restrict__ ps0, const float* __restrict__ pwt0,
    const float* __restrict__ ps1, const float* __restrict__ pwt1,
    const float* __restrict__ e0, const int* __restrict__ idx0,
    const float* __restrict__ e1, const int* __restrict__ idx1,
    float* __restrict__ partial)
{
    __shared__ float s_sd[RPB][NP];
    __shared__ float s_wn[RPB][NN];
    __shared__ float s_bounds[RPB][C];
    __shared__ float s_rs[RPB][C];
    __shared__ float s_wb[RPB][C];
    __shared__ float s_cdf[RPB][C];
    __shared__ int   s_fe[RPB][C];
    __shared__ float s_ci[RPB][260];
    __shared__ float s_red[RPB];
    __shared__ unsigned long long s_masks[6];

    const int tid = threadIdx.x;
    const int wid = tid >> 6;
    const int lane = tid & 63;

    if (blockIdx.x >= GB_ROW) {
        // ================= HASH part =================
        const int h = blockIdx.x - GB_ROW;
        const int lvlh = (h >= GB_HASH);
        const float* __restrict__ emb = lvlh ? e1 : e0;
        const int*   __restrict__ idx = lvlh ? idx1 : idx0;
        const int base = (lvlh ? h - GB_HASH : h) * 256;
        const int i = base + tid;

        const int seg = idx[i];
        const int head = (i == 0) || (idx[i - 1] != seg);
        unsigned long long m = __ballot(head);
        if (lane == 0) s_masks[wid + 1] = m;
        if (wid == 0) {
            const int j = base - 64 + lane;
            int hh = 0;
            if (j == 0) hh = 1;
            else if (j > 0) hh = (idx[j - 1] != idx[j]);
            unsigned long long mp = __ballot(hh);
            if (lane == 0) s_masks[0] = mp;
        }
        if (wid == 3) {
            const int j = base + 256 + lane;
            int hh = 1;                       // j >= MM: virtual terminator head
            if (j < MM) hh = (idx[j - 1] != idx[j]);
            unsigned long long mn = __ballot(hh);
            if (lane == 0) s_masks[5] = mn;
        }
        __syncthreads();

        const unsigned long long m_prev = s_masks[wid];
        const unsigned long long m_cur  = s_masks[wid + 1];
        const unsigned long long m_next = s_masks[wid + 2];
        const int wb0 = base + (wid << 6);

        const unsigned long long low = m_cur & (~0ULL >> (63 - lane));
        int s;
        if (low) s = wb0 + 63 - __builtin_clzll(low);
        else if (m_prev) s = wb0 - 64 + 63 - __builtin_clzll(m_prev);
        else { s = i; while (s > 0 && idx[s - 1] == seg) --s; }  // run>128: never

        const unsigned long long high =
            (lane < 63) ? (m_cur & (~0ULL << (lane + 1))) : 0ULL;
        int e;
        if (high) e = wb0 + __builtin_ctzll(high);
        else if (m_next) e = wb0 + 64 + __builtin_ctzll(m_next);
        else { e = i + 1; while (e < MM && idx[e] == seg) ++e; }  // never

        const float a = emb[2 * i], b = emb[2 * i + 1];
        float v = (a * a + b * b) / (float)(e - s);

#pragma unroll
        for (int d = 32; d > 0; d >>= 1) v += __shfl_down(v, d, 64);
        if (lane == 0) s_red[wid] = v;
        __syncthreads();
        if (tid == 0)
            partial[blockIdx.x] =
                (s_red[0] + s_red[1] + s_red[2] + s_red[3]) *
                (0.1f / ((float)NSEG * 2.f));
        return;
    }

    // ================= ROW part: one wave per row, wave-private LDS =======
    const int r = blockIdx.x * RPB + wid;

    float* sd  = s_sd[wid];
    float* wn  = s_wn[wid];
    float* bounds = s_bounds[wid];
    float* rs  = s_rs[wid];
    float* wb  = s_wb[wid];
    float* cdf = s_cdf[wid];
    int*   fe  = s_fe[wid];
    float* ci  = s_ci[wid];

    if (lane < NP) sd[lane] = sdist_g[r * NP + lane];
    const float w_l = (lane < NN) ? w_g[r * NN + lane] : 0.f;  // register copy
    WAVE_FENCE();
    float mid_l = 0.f;
    if (lane < NN) {
        wn[lane] = w_l / (sd[lane + 1] - sd[lane] + 1e-8f);
        mid_l    = 0.5f * (sd[lane + 1] + sd[lane]);
    }
    WAVE_FENCE();

    float local = 0.f;

#pragma unroll
    for (int lvl = 0; lvl < 2; ++lvl) {
        const float pw = (lvl == 0) ? 0.01f : 0.005f;
        const int X = (lvl == 0) ? 257 : 97;
        const int NPASS = (lvl == 0) ? 5 : 2;  // ceil(X/64)
        const float* ps  = (lvl == 0) ? ps0 : ps1;
        const float* pwt = (lvl == 0) ? pwt0 : pwt1;

        // ---- stable merge-rank of cat = [sd-pw, sd+pw]; branchless, 2-ILP --
        if (lane < NP) {
            const int i = lane;
            const float dlo = (i > 0)  ? wn[i - 1] : 0.f;
            const float dhi = (i < NN) ? wn[i] : 0.f;
            const float rd = (dhi - dlo) / (2.f * pw);
            const float vlo = sd[i] - pw, vhi = sd[i] + pw;
            unsigned p1 = 0, p2 = 0;  // counts over 49 entries
#pragma unroll
            for (unsigned step = 32; step; step >>= 1) {
                unsigned n1 = p1 + step, n2 = p2 + step;
                float a1 = sd[(n1 <= NP ? n1 : NP) - 1];
                float a2 = sd[(n2 <= NP ? n2 : NP) - 1];
                if (n1 <= NP && a1 + pw < vlo)  p1 = n1;  // 2nd half strictly <
                if (n2 <= NP && a2 - pw <= vhi) p2 = n2;  // 1st half <= (wins ties)
            }
            bounds[i + p1] = vlo; rs[i + p1] = rd;
            bounds[i + p2] = vhi; rs[i + p2] = -rd;
        }
        WAVE_FENCE();

        // ---- parallel scans: lane holds elements k0=2*lane, k1=k0+1 ----
        const int k0 = 2 * lane, k1 = 2 * lane + 1;
        const bool v0 = (k0 <= C - 2), v1 = (k1 <= C - 2);
        float b0 = 0.f, b1 = 0.f, b2 = 0.f, r0 = 0.f, r1 = 0.f;
        if (v0) { b0 = bounds[k0]; b1 = bounds[k0 + 1]; r0 = rs[k0]; }
        if (v1) { b2 = bounds[k1 + 1]; r1 = rs[k1]; }
        const float ds0 = b1 - b0, ds1 = b2 - b1;

        // scan 1: cum1 = cumsum(radio_sorted)
        float pairv = r0 + r1;
        float incl = wscan_add(pairv, lane);
        float excl = __shfl_up(incl, 1, 64); if (lane == 0) excl = 0.f;
        const float cum0 = excl + r0, cum1 = excl + pairv;

        // scan 2: acc2 = cumsum(ds * cum1); rec = max(acc2, 0)
        float y0 = v0 ? ds0 * cum0 : 0.f;
        float y1 = v1 ? ds1 * cum1 : 0.f;
        pairv = y0 + y1;
        incl = wscan_add(pairv, lane);
        excl = __shfl_up(incl, 1, 64); if (lane == 0) excl = 0.f;
        const float rec0 = v0 ? fmaxf(excl + y0, 0.f) : 0.f;
        const float rec1 = v1 ? fmaxf(excl + pairv, 0.f) : 0.f;

        // scan 3: cdf = cumsum(0.5*(rec[k]+rec[k-1])*ds[k]), rec[-1]=0
        float rprev = __shfl_up(rec1, 1, 64); if (lane == 0) rprev = 0.f;
        float t0 = v0 ? 0.5f * (rec0 + rprev) * ds0 : 0.f;
        float t1 = v1 ? 0.5f * (rec1 + rec0) * ds1 : 0.f;
        pairv = t0 + t1;
        incl = wscan_add(pairv, lane);
        excl = __shfl_up(incl, 1, 64); if (lane == 0) excl = 0.f;
        const float c0 = excl + t0;     // cdf[j0], j0 = k0+1
        const float c1 = excl + pairv;  // cdf[j1], j1 = k1+1

        // first_eq (plateau start) = inclusive max-scan of (changed ? j : 0)
        float cprev = __shfl_up(c1, 1, 64); if (lane == 0) cprev = 0.f;
        const int j0 = k0 + 1, j1 = k1 + 1;
        const int m0 = (v0 && c0 != cprev) ? j0 : 0;
        const int m1 = (v1 && c1 != c0) ? j1 : 0;
        int pm = max(m0, m1);
        int inclm = wscan_max(pm, lane);
        int exclm = __shfl_up(inclm, 1, 64); if (lane == 0) exclm = 0;

        if (lane == 0) { wb[0] = 0.f; cdf[0] = 0.f; fe[0] = 0; }
        if (v0) { wb[j0] = rec0; cdf[j0] = c0; fe[j0] = max(exclm, m0); }
        if (v1) { wb[j1] = rec1; cdf[j1] = c1; fe[j1] = max(exclm, pm); }
        const float cdf_last = __shfl(c1, (C - 2) >> 1, 64);  // cdf[C-1]
        WAVE_FENCE();

        // ---- sorted_interp_quad: NPASS independent branchless searches ----
        {
            float xv[5];
            int   jv[5];
#pragma unroll
            for (int p = 0; p < NPASS; ++p) {
                const int t = p * 64 + lane;
                const int tc = t < X ? t : X - 1;
                xv[p] = ps[r * X + tc];
            }
#pragma unroll
            for (unsigned step = 64; step; step >>= 1) {
#pragma unroll
                for (int p = 0; p < NPASS; ++p) {
                    unsigned pos = (unsigned)(p == 0 ? 0 : 0);  // placeholder
                }
            }
            // fixed-step lower-bound, all NPASS searches interleaved for ILP
            unsigned posv[5];
#pragma unroll
            for (int p = 0; p < NPASS; ++p) posv[p] = 0u;
#pragma unroll
            for (unsigned step = 64; step; step >>= 1) {
#pragma unroll
                for (int p = 0; p < NPASS; ++p) {
                    const unsigned np_ = posv[p] + step;
                    const float bv = bounds[(np_ <= C ? np_ : C) - 1];
                    if (np_ <= C && bv <= xv[p]) posv[p] = np_;
                }
            }
#pragma unroll
            for (int p = 0; p < NPASS; ++p) jv[p] = (int)posv[p] - 1;

#pragma unroll
            for (int p = 0; p < NPASS; ++p) {
                const int t = p * 64 + lane;
                const float x = xv[p];
                const int j = jv[p];
                float res = 0.f;
                if (j >= 0) {
                    const float fcdf0 = cdf[j];
                    const int   i0   = fe[j];      // argmax tie -> plateau start
                    const float xp0  = bounds[j];
                    float xp1; int i1;
                    if (j == C - 1) { xp1 = bounds[C - 1]; i1 = 0; }
                    else {
                        xp1 = bounds[j + 1];
                        i1 = (cdf[j + 1] == cdf_last) ? 0 : (j + 1);  // flat tail
                    }
                    const float fpdf0 = wb[i0], fpdf1 = wb[i1];
                    const float dx = x - xp0, den = xp1 - xp0;
                    float off;
                    if (den != 0.f) off = dx / den;
                    else off = (dx == 0.f) ? 0.f : ((dx > 0.f) ? 1.f : 0.f);
                    off = fminf(fmaxf(off, 0.f), 1.f);
                    res = fcdf0 + dx * (fpdf0 + fpdf1 * off + fpdf0 * (1.f - off)) * 0.5f;
                }
                if (t < X) ci[t] = res;
            }
        }
        WAVE_FENCE();

        float lsum = 0.f;
#pragma unroll
        for (int p = 0; p < NPASS; ++p) {
            const int t = p * 64 + lane;
            if (t < X - 1) {
                const float ws = ci[t + 1] - ci[t];
                const float pv = pwt[r * (X - 1) + t];
                const float d = fmaxf(ws - pv, 0.f);
                lsum += d * d / (pv + 1e-5f);
            }
        }
        local += lsum * (1.0f / ((float)R * (float)(X - 1)));  // W_INTER = 1
        WAVE_FENCE();  // before LDS reuse by next level
    }

    // ---- distortion loss, O(N) via prefix sums (mid sorted ascending) ----
    // sum_m w_m |mid_n - mid_m| = mid_n(2P_n - W) - 2Q_n + TQ,
    //   P_n = sum_{m<=n} w_m,  Q_n = sum_{m<=n} w_m mid_m.
    {
        const float wm = w_l * mid_l;
        const float P = wscan_add(w_l, lane);   // lanes >= NN contribute 0
        const float Q = wscan_add(wm, lane);
        const float W = __shfl(P, 63, 64);
        const float TQ = __shfl(Q, 63, 64);
        float term = 0.f;
        if (lane < NN)
            term = w_l * (mid_l * (2.f * P - W) - 2.f * Q + TQ);
        local += term * (0.01f / (float)R);
        if (lane < NN) {
            const float dd = sd[lane + 1] - sd[lane];
            local += (w_l * w_l * dd) * (0.01f / (3.f * (float)R));
        }
    }

    // ---- rgb loss ----
    if (lane < 3) {
        const float e = pd[r * 3 + lane] - gt[r * 3 + lane];
        local += e * e * (1.0f / ((float)R * 3.f));
    }

    // ---- wave reduce, one real barrier, plain partial store ----
#pragma unroll
    for (int d = 32; d > 0; d >>= 1) local += __shfl_down(local, d, 64);
    if (lane == 0) s_red[wid] = local;
    __syncthreads();
    if (tid == 0)
        partial[blockIdx.x] = s_red[0] + s_red[1] + s_red[2] + s_red[3];
}

// ---------------------------------------------------------------------------
// Final reduction of per-block partials (single block, no atomics).
// ---------------------------------------------------------------------------
__global__ __launch_bounds__(256) void reduce_kernel(
    const float* __restrict__ partial, float* __restrict__ out)
{
    float s = 0.f;
    for (int t = threadIdx.x; t < GRID; t += 256) s += partial[t];
    const int lane = threadIdx.x & 63;
#pragma unroll
    for (int d = 32; d > 0; d >>= 1) s += __shfl_down(s, d, 64);
    __shared__ float sred[4];
    if (lane == 0) sred[threadIdx.x >> 6] = s;
    __syncthreads();
    if (threadIdx.x == 0)
        out[0] = sred[0] + sred[1] + sred[2] + sred[3];
}

extern "C" void kernel_launch(void* const* d_in, const int* in_sizes, int n_in,
                              void* d_out, int out_size, void* d_ws, size_t ws_size,
                              hipStream_t stream)
{
    const float* pd  = (const float*)d_in[0];
    const float* gt  = (const float*)d_in[1];
    const float* sd  = (const float*)d_in[2];
    const float* w   = (const float*)d_in[3];
    const float* ps0 = (const float*)d_in[4];
    const float* pw0 = (const float*)d_in[5];
    const float* ps1 = (const float*)d_in[6];
    const float* pw1 = (const float*)d_in[7];
    const float* e0  = (const float*)d_in[8];
    const float* e1  = (const float*)d_in[9];
    const int* i0    = (const int*)d_in[10];
    const int* i1    = (const int*)d_in[11];

    float* partial = (float*)d_ws;  // GRID floats; every slot written each call

    hipLaunchKernelGGL(fused_kernel, dim3(GRID), dim3(256), 0, stream,
                       pd, gt, sd, w, ps0, pw0, ps1, pw1,
                       e0, i0, e1, i1, partial);
    hipLaunchKernelGGL(reduce_kernel, dim3(1), dim3(256), 0, stream,
                       partial, (float*)d_out);
}

// Round 7
// 98.796 us; speedup vs baseline: 1.5329x; 1.0432x over previous
//
#include <hip/hip_runtime.h>

#define R 4096
#define NN 48
#define NP 49        // N+1
#define C 98         // 2N+2
#define NSEG 65536
#define MM (R * NN)  // 196608
#define RPB 4        // rows (waves) per row-block
#define GB_ROW (R / RPB)            // 1024
#define GB_HASH (MM / 256)          // 768 per level
#define GRID (GB_ROW + 2 * GB_HASH) // 2560

// Zero-cost compiler fence: row LDS is wave-private; DS ops from one wave are
// processed in order, so no s_barrier needed — just block compiler reordering.
#define WAVE_FENCE() __builtin_amdgcn_wave_barrier()

__device__ __forceinline__ float wscan_add(float v, int lane) {
#pragma unroll
    for (int d = 1; d < 64; d <<= 1) {
        float t = __shfl_up(v, d, 64);
        if (lane >= d) v += t;
    }
    return v;
}

__device__ __forceinline__ int wscan_max(int v, int lane) {
#pragma unroll
    for (int d = 1; d < 64; d <<= 1) {
        int t = __shfl_up(v, d, 64);
        if (lane >= d) v = max(v, t);
    }
    return v;
}

// ---------------------------------------------------------------------------
// Fused kernel. Blocks [0, GB_ROW): per-row losses, ONE wave per row, 4 rows
// per block, wave-private LDS, wave fences only (one s_barrier at the end).
// Blocks [GB_ROW, GRID): hash-decay, ballot-based run lengths.
// Every block writes partial[blockIdx.x] with a plain store (no atomics).
// ---------------------------------------------------------------------------
__global__ __launch_bounds__(256) void fused_kernel(
    const float* __restrict__ pd, const float* __restrict__ gt,
    const float* __restrict__ sdist_g, const float* __restrict__ w_g,
    const float* __restrict__ ps0, const float* __restrict__ pwt0,
    const float* __restrict__ ps1, const float* __restrict__ pwt1,
    const float* __restrict__ e0, const int* __restrict__ idx0,
    const float* __restrict__ e1, const int* __restrict__ idx1,
    float* __restrict__ partial)
{
    __shared__ float s_sd[RPB][NP];
    __shared__ float s_wn[RPB][NN];
    __shared__ float s_bounds[RPB][C];
    __shared__ float s_rs[RPB][C];
    __shared__ float s_wb[RPB][C];
    __shared__ float s_cdf[RPB][C];
    __shared__ int   s_fe[RPB][C];
    __shared__ float s_red[RPB];
    __shared__ unsigned long long s_masks[6];

    const int tid = threadIdx.x;
    const int wid = tid >> 6;
    const int lane = tid & 63;

    if (blockIdx.x >= GB_ROW) {
        // ================= HASH part =================
        const int h = blockIdx.x - GB_ROW;
        const int lvlh = (h >= GB_HASH);
        const float* __restrict__ emb = lvlh ? e1 : e0;
        const int*   __restrict__ idx = lvlh ? idx1 : idx0;
        const int base = (lvlh ? h - GB_HASH : h) * 256;
        const int i = base + tid;

        const float2 ab = ((const float2*)emb)[i];     // vectorized 8B load
        const int seg = idx[i];
        const int head = (i == 0) || (idx[i - 1] != seg);
        unsigned long long m = __ballot(head);
        if (lane == 0) s_masks[wid + 1] = m;
        if (wid == 0) {
            const int j = base - 64 + lane;
            int hh = 0;
            if (j == 0) hh = 1;
            else if (j > 0) hh = (idx[j - 1] != idx[j]);
            unsigned long long mp = __ballot(hh);
            if (lane == 0) s_masks[0] = mp;
        }
        if (wid == 3) {
            const int j = base + 256 + lane;
            int hh = 1;                       // j >= MM: virtual terminator head
            if (j < MM) hh = (idx[j - 1] != idx[j]);
            unsigned long long mn = __ballot(hh);
            if (lane == 0) s_masks[5] = mn;
        }
        __syncthreads();

        const unsigned long long m_prev = s_masks[wid];
        const unsigned long long m_cur  = s_masks[wid + 1];
        const unsigned long long m_next = s_masks[wid + 2];
        const int wb0 = base + (wid << 6);

        const unsigned long long low = m_cur & (~0ULL >> (63 - lane));
        int s;
        if (low) s = wb0 + 63 - __builtin_clzll(low);
        else if (m_prev) s = wb0 - 64 + 63 - __builtin_clzll(m_prev);
        else { s = i; while (s > 0 && idx[s - 1] == seg) --s; }  // run>128: never

        const unsigned long long high =
            (lane < 63) ? (m_cur & (~0ULL << (lane + 1))) : 0ULL;
        int e;
        if (high) e = wb0 + __builtin_ctzll(high);
        else if (m_next) e = wb0 + 64 + __builtin_ctzll(m_next);
        else { e = i + 1; while (e < MM && idx[e] == seg) ++e; }  // never

        float v = (ab.x * ab.x + ab.y * ab.y) / (float)(e - s);

#pragma unroll
        for (int d = 32; d > 0; d >>= 1) v += __shfl_down(v, d, 64);
        if (lane == 0) s_red[wid] = v;
        __syncthreads();
        if (tid == 0)
            partial[blockIdx.x] =
                (s_red[0] + s_red[1] + s_red[2] + s_red[3]) *
                (0.1f / ((float)NSEG * 2.f));
        return;
    }

    // ================= ROW part: one wave per row, wave-private LDS =======
    const int r = blockIdx.x * RPB + wid;

    float* sd  = s_sd[wid];
    float* wn  = s_wn[wid];
    float* bounds = s_bounds[wid];
    float* rs  = s_rs[wid];
    float* wb  = s_wb[wid];
    float* cdf = s_cdf[wid];
    int*   fe  = s_fe[wid];

    if (lane < NP) sd[lane] = sdist_g[r * NP + lane];
    const float w_l = (lane < NN) ? w_g[r * NN + lane] : 0.f;  // register copy
    WAVE_FENCE();
    float mid_l = 0.f;
    if (lane < NN) {
        wn[lane] = w_l / (sd[lane + 1] - sd[lane] + 1e-8f);
        mid_l    = 0.5f * (sd[lane + 1] + sd[lane]);
    }
    WAVE_FENCE();

    float local = 0.f;

#pragma unroll
    for (int lvl = 0; lvl < 2; ++lvl) {
        const float pw = (lvl == 0) ? 0.01f : 0.005f;
        const int X = (lvl == 0) ? 257 : 97;
        const int NPASS = (lvl == 0) ? 5 : 2;  // ceil(X/64)
        const float* ps  = (lvl == 0) ? ps0 : ps1;
        const float* pwt = (lvl == 0) ? pwt0 : pwt1;

        // ---- stable merge-rank of cat = [sd-pw, sd+pw]; branchless, 2-ILP --
        if (lane < NP) {
            const int i = lane;
            const float dlo = (i > 0)  ? wn[i - 1] : 0.f;
            const float dhi = (i < NN) ? wn[i] : 0.f;
            const float rd = (dhi - dlo) / (2.f * pw);
            const float vlo = sd[i] - pw, vhi = sd[i] + pw;
            unsigned p1 = 0, p2 = 0;  // counts over 49 entries
#pragma unroll
            for (unsigned step = 32; step; step >>= 1) {
                unsigned n1 = p1 + step, n2 = p2 + step;
                float a1 = sd[(n1 <= NP ? n1 : NP) - 1];
                float a2 = sd[(n2 <= NP ? n2 : NP) - 1];
                if (n1 <= NP && a1 + pw < vlo)  p1 = n1;  // 2nd half strictly <
                if (n2 <= NP && a2 - pw <= vhi) p2 = n2;  // 1st half <= (wins ties)
            }
            bounds[i + p1] = vlo; rs[i + p1] = rd;
            bounds[i + p2] = vhi; rs[i + p2] = -rd;
        }
        WAVE_FENCE();

        // ---- parallel scans: lane holds elements k0=2*lane, k1=k0+1 ----
        const int k0 = 2 * lane, k1 = 2 * lane + 1;
        const bool v0 = (k0 <= C - 2), v1 = (k1 <= C - 2);
        float b0 = 0.f, b1 = 0.f, b2 = 0.f, r0 = 0.f, r1 = 0.f;
        if (v0) { b0 = bounds[k0]; b1 = bounds[k0 + 1]; r0 = rs[k0]; }
        if (v1) { b2 = bounds[k1 + 1]; r1 = rs[k1]; }
        const float ds0 = b1 - b0, ds1 = b2 - b1;

        // scan 1: cum1 = cumsum(radio_sorted)
        float pairv = r0 + r1;
        float incl = wscan_add(pairv, lane);
        float excl = __shfl_up(incl, 1, 64); if (lane == 0) excl = 0.f;
        const float cum0 = excl + r0, cum1 = excl + pairv;

        // scan 2: acc2 = cumsum(ds * cum1); rec = max(acc2, 0)
        float y0 = v0 ? ds0 * cum0 : 0.f;
        float y1 = v1 ? ds1 * cum1 : 0.f;
        pairv = y0 + y1;
        incl = wscan_add(pairv, lane);
        excl = __shfl_up(incl, 1, 64); if (lane == 0) excl = 0.f;
        const float rec0 = v0 ? fmaxf(excl + y0, 0.f) : 0.f;
        const float rec1 = v1 ? fmaxf(excl + pairv, 0.f) : 0.f;

        // scan 3: cdf = cumsum(0.5*(rec[k]+rec[k-1])*ds[k]), rec[-1]=0
        float rprev = __shfl_up(rec1, 1, 64); if (lane == 0) rprev = 0.f;
        float t0 = v0 ? 0.5f * (rec0 + rprev) * ds0 : 0.f;
        float t1 = v1 ? 0.5f * (rec1 + rec0) * ds1 : 0.f;
        pairv = t0 + t1;
        incl = wscan_add(pairv, lane);
        excl = __shfl_up(incl, 1, 64); if (lane == 0) excl = 0.f;
        const float c0 = excl + t0;     // cdf[j0], j0 = k0+1
        const float c1 = excl + pairv;  // cdf[j1], j1 = k1+1

        // first_eq (plateau start) = inclusive max-scan of (changed ? j : 0)
        float cprev = __shfl_up(c1, 1, 64); if (lane == 0) cprev = 0.f;
        const int j0 = k0 + 1, j1 = k1 + 1;
        const int m0 = (v0 && c0 != cprev) ? j0 : 0;
        const int m1 = (v1 && c1 != c0) ? j1 : 0;
        int pm = max(m0, m1);
        int inclm = wscan_max(pm, lane);
        int exclm = __shfl_up(inclm, 1, 64); if (lane == 0) exclm = 0;

        if (lane == 0) { wb[0] = 0.f; cdf[0] = 0.f; fe[0] = 0; }
        if (v0) { wb[j0] = rec0; cdf[j0] = c0; fe[j0] = max(exclm, m0); }
        if (v1) { wb[j1] = rec1; cdf[j1] = c1; fe[j1] = max(exclm, pm); }
        const float cdf_last = __shfl(c1, (C - 2) >> 1, 64);  // cdf[C-1]
        WAVE_FENCE();

        // ---- sorted_interp_quad: NPASS interleaved branchless searches ----
        float resv[5];
        {
            float xv[5], pvv[5];
#pragma unroll
            for (int p = 0; p < NPASS; ++p) {
                const int t = p * 64 + lane;
                xv[p] = ps[r * X + (t < X ? t : X - 1)];
                pvv[p] = pwt[r * (X - 1) + (t < X - 1 ? t : 0)];  // prefetch
            }
            // fixed-step lower-bound, all NPASS searches interleaved for ILP
            unsigned posv[5];
#pragma unroll
            for (int p = 0; p < NPASS; ++p) posv[p] = 0u;
#pragma unroll
            for (unsigned step = 64; step; step >>= 1) {
#pragma unroll
                for (int p = 0; p < NPASS; ++p) {
                    const unsigned np_ = posv[p] + step;
                    const float bv = bounds[(np_ <= C ? np_ : C) - 1];
                    if (np_ <= C && bv <= xv[p]) posv[p] = np_;
                }
            }
#pragma unroll
            for (int p = 0; p < NPASS; ++p) {
                const float x = xv[p];
                const int j = (int)posv[p] - 1;
                float res = 0.f;
                if (j >= 0) {
                    const float fcdf0 = cdf[j];
                    const int   i0   = fe[j];      // argmax tie -> plateau start
                    const float xp0  = bounds[j];
                    float xp1; int i1;
                    if (j == C - 1) { xp1 = bounds[C - 1]; i1 = 0; }
                    else {
                        xp1 = bounds[j + 1];
                        i1 = (cdf[j + 1] == cdf_last) ? 0 : (j + 1);  // flat tail
                    }
                    const float fpdf0 = wb[i0], fpdf1 = wb[i1];
                    const float dx = x - xp0, den = xp1 - xp0;
                    float off;
                    if (den != 0.f) off = dx / den;
                    else off = (dx == 0.f) ? 0.f : ((dx > 0.f) ? 1.f : 0.f);
                    off = fminf(fmaxf(off, 0.f), 1.f);
                    res = fcdf0 + dx * (fpdf0 + fpdf1 * off + fpdf0 * (1.f - off)) * 0.5f;
                }
                resv[p] = res;
            }

            // ---- w_s = diff(res) via shuffles — no LDS round-trip ----
            float lsum = 0.f;
#pragma unroll
            for (int p = 0; p < NPASS; ++p) {
                float nxt = __shfl_down(resv[p], 1, 64);
                if (p + 1 < NPASS) {
                    const float head = __shfl(resv[p + 1], 0, 64);
                    if (lane == 63) nxt = head;
                }
                const int t = p * 64 + lane;
                if (t < X - 1) {
                    const float ws = nxt - resv[p];
                    const float d = fmaxf(ws - pvv[p], 0.f);
                    lsum += d * d / (pvv[p] + 1e-5f);
                }
            }
            local += lsum * (1.0f / ((float)R * (float)(X - 1)));  // W_INTER=1
        }
        WAVE_FENCE();  // before LDS reuse by next level
    }

    // ---- distortion loss, O(N) via prefix sums (mid sorted ascending) ----
    // sum_m w_m |mid_n - mid_m| = mid_n(2P_n - W) - 2Q_n + TQ,
    //   P_n = sum_{m<=n} w_m,  Q_n = sum_{m<=n} w_m mid_m.
    {
        const float wm = w_l * mid_l;
        const float P = wscan_add(w_l, lane);   // lanes >= NN contribute 0
        const float Q = wscan_add(wm, lane);
        const float W = __shfl(P, 63, 64);
        const float TQ = __shfl(Q, 63, 64);
        float term = 0.f;
        if (lane < NN)
            term = w_l * (mid_l * (2.f * P - W) - 2.f * Q + TQ);
        local += term * (0.01f / (float)R);
        if (lane < NN) {
            const float dd = sd[lane + 1] - sd[lane];
            local += (w_l * w_l * dd) * (0.01f / (3.f * (float)R));
        }
    }

    // ---- rgb loss ----
    if (lane < 3) {
        const float e = pd[r * 3 + lane] - gt[r * 3 + lane];
        local += e * e * (1.0f / ((float)R * 3.f));
    }

    // ---- wave reduce, one real barrier, plain partial store ----
#pragma unroll
    for (int d = 32; d > 0; d >>= 1) local += __shfl_down(local, d, 64);
    if (lane == 0) s_red[wid] = local;
    __syncthreads();
    if (tid == 0)
        partial[blockIdx.x] = s_red[0] + s_red[1] + s_red[2] + s_red[3];
}

// ---------------------------------------------------------------------------
// Final reduction of per-block partials (single block, no atomics).
// ---------------------------------------------------------------------------
__global__ __launch_bounds__(256) void reduce_kernel(
    const float* __restrict__ partial, float* __restrict__ out)
{
    float s = 0.f;
    for (int t = threadIdx.x; t < GRID; t += 256) s += partial[t];
    const int lane = threadIdx.x & 63;
#pragma unroll
    for (int d = 32; d > 0; d >>= 1) s += __shfl_down(s, d, 64);
    __shared__ float sred[4];
    if (lane == 0) sred[threadIdx.x >> 6] = s;
    __syncthreads();
    if (threadIdx.x == 0)
        out[0] = sred[0] + sred[1] + sred[2] + sred[3];
}

extern "C" void kernel_launch(void* const* d_in, const int* in_sizes, int n_in,
                              void* d_out, int out_size, void* d_ws, size_t ws_size,
                              hipStream_t stream)
{
    const float* pd  = (const float*)d_in[0];
    const float* gt  = (const float*)d_in[1];
    const float* sd  = (const float*)d_in[2];
    const float* w   = (const float*)d_in[3];
    const float* ps0 = (const float*)d_in[4];
    const float* pw0 = (const float*)d_in[5];
    const float* ps1 = (const float*)d_in[6];
    const float* pw1 = (const float*)d_in[7];
    const float* e0  = (const float*)d_in[8];
    const float* e1  = (const float*)d_in[9];
    const int* i0    = (const int*)d_in[10];
    const int* i1    = (const int*)d_in[11];

    float* partial = (float*)d_ws;  // GRID floats; every slot written each call

    hipLaunchKernelGGL(fused_kernel, dim3(GRID), dim3(256), 0, stream,
                       pd, gt, sd, w, ps0, pw0, ps1, pw1,
                       e0, i0, e1, i1, partial);
    hipLaunchKernelGGL(reduce_kernel, dim3(1), dim3(256), 0, stream,
                       partial, (float*)d_out);
}